// Round 1
// baseline (499.342 us; speedup 1.0000x reference)
//
#include <hip/hip_runtime.h>

typedef _Float16 f16;
typedef __attribute__((ext_vector_type(8))) _Float16 f16x8;
typedef __attribute__((ext_vector_type(8))) short s16x8;
typedef __attribute__((ext_vector_type(4))) float f32x4;
typedef __attribute__((ext_vector_type(4))) unsigned short us16x4;

#define DIN   1024
#define DD    128
#define NBAT  4
#define TLEN  4096
#define NROWS (NBAT * TLEN)   // 16384

// ---------- scalar conversions ----------
static __device__ __forceinline__ unsigned short f2bf(float f) {
  unsigned int u = __builtin_bit_cast(unsigned int, f);
  u = (u + 0x7fffu + ((u >> 16) & 1u)) >> 16;
  return (unsigned short)u;
}
static __device__ __forceinline__ float bf2f(unsigned short h) {
  return __builtin_bit_cast(float, (unsigned int)h << 16);
}
static __device__ __forceinline__ unsigned short f2h(float f) {
  _Float16 h = (_Float16)f;
  return __builtin_bit_cast(unsigned short, h);
}

// ---------- LDS bank-conflict swizzles (16B granules, key = row&7) ----------
// 128-elem f16 row: 16 granules of 8 elems
static __device__ __forceinline__ int swz128(int d, int key) {
  return ((((d >> 3) ^ key) & 15) << 3) | (d & 7);
}
// 64-elem row: 8 granules of 8 elems
static __device__ __forceinline__ int swz64(int c, int key) {
  return ((((c >> 3) ^ key) & 7) << 3) | (c & 7);
}

// ---------- async global->LDS, width 16 ----------
typedef __attribute__((address_space(1))) const unsigned int* gas1_t;
typedef __attribute__((address_space(3))) unsigned int* las3_t;
static __device__ __forceinline__ void gload16(const void* g, void* l) {
  __builtin_amdgcn_global_load_lds((gas1_t)g, (las3_t)l, 16, 0, 0);
}

// =====================================================================
// Kernel 1: build W' = bf16 hi/lo of [Wq|Wk|Wv]^T, layout [col 0..383][DIN],
// pre-swizzled in 64-elem chunks with key = col&7 (consumer LDS row = local col).
// =====================================================================
__global__ void build_wt(const float* __restrict__ Wq, const float* __restrict__ Wk,
                         const float* __restrict__ Wv,
                         unsigned short* __restrict__ Wh, unsigned short* __restrict__ Wl) {
  int col = blockIdx.x;                 // 0..383
  const float* W = (col < 128) ? Wq : (col < 256 ? Wk : Wv);
  int j = col & 127;
  for (int kk = (int)threadIdx.x; kk < DIN; kk += blockDim.x) {
    float w = W[(size_t)kk * DD + j];
    unsigned short h = f2bf(w);
    unsigned short l = f2bf(w - bf2f(h));
    int c64 = kk >> 6, w64 = kk & 63;
    int kks = (c64 << 6) + swz64(w64, col & 7);
    Wh[(size_t)col * DIN + kks] = h;
    Wl[(size_t)col * DIN + kks] = l;
  }
}

// =====================================================================
// Kernel 2: projection GEMM  C[16384][384] = x @ W' with bf16 hi/lo 3-product.
// 128x128 tile, BK=64, 4 waves (2x2, 64x64 each), 16x16x32 bf16 MFMA.
// Outputs q,k (f16, [row][swz d]) and v (f16, transposed [n][d][swz t]).
// =====================================================================
__global__ __launch_bounds__(256, 2) void proj_qkv(
    const float* __restrict__ x,
    const unsigned short* __restrict__ Wh, const unsigned short* __restrict__ Wl,
    unsigned short* __restrict__ qws, unsigned short* __restrict__ kws,
    unsigned short* __restrict__ vws) {
  __shared__ __align__(16) unsigned short Ah[128 * 64];
  __shared__ __align__(16) unsigned short Al[128 * 64];
  __shared__ __align__(16) unsigned short Bh[128 * 64];
  __shared__ __align__(16) unsigned short Bl[128 * 64];

  const int tid = (int)threadIdx.x;
  const int lane = tid & 63;
  const int wid = tid >> 6;
  const int t0 = blockIdx.x * 128;     // row tile base (flattened n*T+t)
  const int ct = blockIdx.y;           // 0=q, 1=k, 2=v

  const int rbase = (wid >> 1) * 64;
  const int cbase = (wid & 1) * 64;

  f32x4 acc[4][4];
#pragma unroll
  for (int m = 0; m < 4; ++m)
#pragma unroll
    for (int n = 0; n < 4; ++n) acc[m][n] = f32x4{0.f, 0.f, 0.f, 0.f};

  for (int kr = 0; kr < 16; ++kr) {
    // ---- stage x tile [128][64] fp32 -> hi/lo bf16 in LDS (swizzled) ----
#pragma unroll
    for (int rr = 0; rr < 8; ++rr) {
      int idx = rr * 256 + tid;
      int row = idx >> 4;
      int c0 = (idx & 15) * 4;
      f32x4 xv = *(const f32x4*)(x + (size_t)(t0 + row) * DIN + kr * 64 + c0);
      int g = swz64(c0, row & 7);
      unsigned short hs0 = f2bf(xv[0]), hs1 = f2bf(xv[1]), hs2 = f2bf(xv[2]), hs3 = f2bf(xv[3]);
      us16x4 hv = {hs0, hs1, hs2, hs3};
      us16x4 lv = {f2bf(xv[0] - bf2f(hs0)), f2bf(xv[1] - bf2f(hs1)),
                   f2bf(xv[2] - bf2f(hs2)), f2bf(xv[3] - bf2f(hs3))};
      *(us16x4*)&Ah[row * 64 + g] = hv;
      *(us16x4*)&Al[row * 64 + g] = lv;
    }
    // ---- stage W' tiles via global_load_lds (pre-swizzled source) ----
#pragma unroll
    for (int rr = 0; rr < 4; ++rr) {
      int idx = rr * 256 + tid;
      int row = idx >> 3;
      int g = idx & 7;
      size_t gbyte = ((size_t)(ct * 128 + row) * DIN + (size_t)kr * 64) * 2 + (size_t)g * 16;
      gload16((const char*)Wh + gbyte, (char*)Bh + (size_t)idx * 16);
      gload16((const char*)Wl + gbyte, (char*)Bl + (size_t)idx * 16);
    }
    __syncthreads();

#pragma unroll
    for (int kc = 0; kc < 2; ++kc) {
      s16x8 ah[4], al[4], bh[4], bl[4];
#pragma unroll
      for (int m = 0; m < 4; ++m) {
        int r = rbase + m * 16 + (lane & 15);
        int g = ((kc * 4 + (lane >> 4)) ^ (r & 7)) * 8;
        ah[m] = *(const s16x8*)&Ah[r * 64 + g];
        al[m] = *(const s16x8*)&Al[r * 64 + g];
      }
#pragma unroll
      for (int n = 0; n < 4; ++n) {
        int c = cbase + n * 16 + (lane & 15);
        int g = ((kc * 4 + (lane >> 4)) ^ (c & 7)) * 8;
        bh[n] = *(const s16x8*)&Bh[c * 64 + g];
        bl[n] = *(const s16x8*)&Bl[c * 64 + g];
      }
#pragma unroll
      for (int m = 0; m < 4; ++m)
#pragma unroll
        for (int n = 0; n < 4; ++n) {
          acc[m][n] = __builtin_amdgcn_mfma_f32_16x16x32_bf16(ah[m], bh[n], acc[m][n], 0, 0, 0);
          acc[m][n] = __builtin_amdgcn_mfma_f32_16x16x32_bf16(ah[m], bl[n], acc[m][n], 0, 0, 0);
          acc[m][n] = __builtin_amdgcn_mfma_f32_16x16x32_bf16(al[m], bh[n], acc[m][n], 0, 0, 0);
        }
    }
    __syncthreads();
  }

  // ---- write q/k/v as f16 with consumer swizzles ----
#pragma unroll
  for (int m = 0; m < 4; ++m)
#pragma unroll
    for (int n = 0; n < 4; ++n)
#pragma unroll
      for (int e = 0; e < 4; ++e) {
        int t = t0 + rbase + m * 16 + (lane >> 4) * 4 + e;  // 0..16383
        int d = cbase + n * 16 + (lane & 15);               // 0..127
        unsigned short hv = f2h(acc[m][n][e]);
        if (ct == 0) {
          qws[(size_t)t * DD + swz128(d, t & 7)] = hv;
        } else if (ct == 1) {
          kws[(size_t)t * DD + swz128(d, t & 7)] = hv;
        } else {
          int nb = t >> 12, tl = t & (TLEN - 1);
          int ch = tl >> 7, wpos = tl & 127;
          int tls = ch * 128 + swz128(wpos, d & 7);
          vws[((size_t)nb * DD + d) * TLEN + tls] = hv;
        }
      }
}

// =====================================================================
// Kernel 3: fused causal attention per (n, 64-row q-tile).
// Phase A: Z = sum of masked exp(s) (QK^T). Phase B: recompute s (bitwise
// identical), write att = exp(s)/Z (fp32), PV-accumulate out via fp16 MFMA.
// 4 waves x 16 q-rows; k/v tiles of 128 staged via global_load_lds.
// =====================================================================
__global__ __launch_bounds__(256, 2) void attn_fused(
    const unsigned short* __restrict__ qws, const unsigned short* __restrict__ kws,
    const unsigned short* __restrict__ vws, float* __restrict__ out,
    float* __restrict__ att) {
  __shared__ __align__(16) unsigned short kl[128 * 128];
  __shared__ __align__(16) unsigned short vl[128 * 128];
  __shared__ __align__(16) unsigned short qp[64 * 128];   // q staging, then p buffer

  const int tid = (int)threadIdx.x;
  const int lane = tid & 63;
  const int wid = tid >> 6;
  const int qi = blockIdx.x;    // 0..63
  const int n = blockIdx.y;     // 0..3
  const int t0 = qi * 64;

  // ---- stage q tile (contiguous, pre-swizzled) ----
  {
    const char* gq = (const char*)(qws + (size_t)(n * TLEN + t0) * DD);
#pragma unroll
    for (int rr = 0; rr < 4; ++rr) {
      int idx = rr * 256 + tid;
      gload16(gq + (size_t)idx * 16, (char*)qp + (size_t)idx * 16);
    }
  }
  __syncthreads();
  f16x8 qa[4];
  {
    int r = wid * 16 + (lane & 15);
#pragma unroll
    for (int kc = 0; kc < 4; ++kc) {
      int g = ((kc * 4 + (lane >> 4)) ^ (r & 7)) * 8;
      qa[kc] = *(const f16x8*)&qp[r * 128 + g];
    }
  }
  __syncthreads();  // all waves done reading qp before it is reused for p

  const int jmax = (t0 + 63) >> 7;
  const int rowg0 = t0 + wid * 16 + (lane >> 4) * 4;

  // ================= Phase A: row sums Z =================
  float zacc[4] = {0.f, 0.f, 0.f, 0.f};
  for (int j = 0; j <= jmax; ++j) {
    const char* gk = (const char*)(kws + (size_t)(n * TLEN + j * 128) * DD);
#pragma unroll
    for (int rr = 0; rr < 8; ++rr) {
      int idx = rr * 256 + tid;
      gload16(gk + (size_t)idx * 16, (char*)kl + (size_t)idx * 16);
    }
    __syncthreads();
#pragma unroll
    for (int fc = 0; fc < 8; ++fc) {
      f32x4 s = f32x4{0.f, 0.f, 0.f, 0.f};
      int rc = fc * 16 + (lane & 15);
#pragma unroll
      for (int kc = 0; kc < 4; ++kc) {
        int g = ((kc * 4 + (lane >> 4)) ^ (rc & 7)) * 8;
        f16x8 kb = *(const f16x8*)&kl[rc * 128 + g];
        s = __builtin_amdgcn_mfma_f32_16x16x32_f16(qa[kc], kb, s, 0, 0, 0);
      }
      int colg = j * 128 + rc;
#pragma unroll
      for (int e = 0; e < 4; ++e) {
        float sv = s[e];
        int rowg = rowg0 + e;
        float ev = (colg <= rowg && sv != 0.0f) ? __expf(sv) : 0.0f;
        zacc[e] += ev;
      }
    }
    __syncthreads();
  }
  float rz[4];
#pragma unroll
  for (int e = 0; e < 4; ++e) {
    float z = zacc[e];
    z += __shfl_xor(z, 1);
    z += __shfl_xor(z, 2);
    z += __shfl_xor(z, 4);
    z += __shfl_xor(z, 8);
    rz[e] = (z > 0.f) ? (1.0f / z) : 0.0f;
  }

  // ================= Phase B: write att, accumulate out =================
  f32x4 oacc[8];
#pragma unroll
  for (int fd = 0; fd < 8; ++fd) oacc[fd] = f32x4{0.f, 0.f, 0.f, 0.f};
  float* attn_base = att + (size_t)n * TLEN * TLEN;

  for (int j = 0; j <= jmax; ++j) {
    const char* gk = (const char*)(kws + (size_t)(n * TLEN + j * 128) * DD);
#pragma unroll
    for (int rr = 0; rr < 8; ++rr) {
      int idx = rr * 256 + tid;
      gload16(gk + (size_t)idx * 16, (char*)kl + (size_t)idx * 16);
    }
    {
      const char* gv = (const char*)(vws + (size_t)n * DD * TLEN);
#pragma unroll
      for (int rr = 0; rr < 8; ++rr) {
        int idx = rr * 256 + tid;
        int d = idx >> 4;
        size_t gb = ((size_t)d * TLEN + (size_t)j * 128) * 2 + (size_t)(idx & 15) * 16;
        gload16(gv + gb, (char*)vl + (size_t)idx * 16);
      }
    }
    __syncthreads();

#pragma unroll
    for (int fc = 0; fc < 8; ++fc) {
      f32x4 s = f32x4{0.f, 0.f, 0.f, 0.f};
      int cloc = fc * 16 + (lane & 15);
#pragma unroll
      for (int kc = 0; kc < 4; ++kc) {
        int g = ((kc * 4 + (lane >> 4)) ^ (cloc & 7)) * 8;
        f16x8 kb = *(const f16x8*)&kl[cloc * 128 + g];
        s = __builtin_amdgcn_mfma_f32_16x16x32_f16(qa[kc], kb, s, 0, 0, 0);
      }
      int colg = j * 128 + cloc;
#pragma unroll
      for (int e = 0; e < 4; ++e) {
        float sv = s[e];
        int rowg = rowg0 + e;
        float ev = (colg <= rowg && sv != 0.0f) ? __expf(sv) : 0.0f;
        float p = ev * rz[e];
        int rq = wid * 16 + (lane >> 4) * 4 + e;
        qp[rq * 128 + swz128(cloc, rq & 7)] = f2h(p);
        attn_base[(size_t)rowg * TLEN + colg] = p;
      }
    }
    __syncthreads();

    // PV: out += p @ v   (A = p rows of this wave, B = v^T tile)
#pragma unroll
    for (int kc = 0; kc < 4; ++kc) {
      int rp = wid * 16 + (lane & 15);
      int gp = ((kc * 4 + (lane >> 4)) ^ (rp & 7)) * 8;
      f16x8 pa = *(const f16x8*)&qp[rp * 128 + gp];
#pragma unroll
      for (int fd = 0; fd < 8; ++fd) {
        int dv = fd * 16 + (lane & 15);
        int gvv = ((kc * 4 + (lane >> 4)) ^ (dv & 7)) * 8;
        f16x8 vb = *(const f16x8*)&vl[dv * 128 + gvv];
        oacc[fd] = __builtin_amdgcn_mfma_f32_16x16x32_f16(pa, vb, oacc[fd], 0, 0, 0);
      }
    }
    __syncthreads();
  }

  // ---- write out [n][t][d] fp32 ----
#pragma unroll
  for (int fd = 0; fd < 8; ++fd)
#pragma unroll
    for (int e = 0; e < 4; ++e) {
      int t = t0 + wid * 16 + (lane >> 4) * 4 + e;
      int d = fd * 16 + (lane & 15);
      out[(size_t)(n * TLEN + t) * DD + d] = oacc[fd][e];
    }

  // ---- zero-fill strictly-upper tiles of att ----
  int c0 = (jmax + 1) * 128;
  f32x4 z4 = f32x4{0.f, 0.f, 0.f, 0.f};
  for (int r = 0; r < 64; ++r) {
    float* rowp = attn_base + (size_t)(t0 + r) * TLEN;
    for (int c = c0 + tid * 4; c < TLEN; c += 1024) {
      *(f32x4*)(rowp + c) = z4;
    }
  }
}

// =====================================================================
extern "C" void kernel_launch(void* const* d_in, const int* in_sizes, int n_in,
                              void* d_out, int out_size, void* d_ws, size_t ws_size,
                              hipStream_t stream) {
  const float* x  = (const float*)d_in[0];
  const float* Wq = (const float*)d_in[1];
  const float* Wk = (const float*)d_in[2];
  const float* Wv = (const float*)d_in[3];

  float* out = (float*)d_out;                              // [4,4096,128]
  float* att = out + (size_t)NBAT * TLEN * DD;             // [4,4096,4096]

  unsigned short* ws = (unsigned short*)d_ws;
  unsigned short* Wh  = ws;                                // 384*1024
  unsigned short* Wl  = Wh + (size_t)384 * DIN;
  unsigned short* qws = Wl + (size_t)384 * DIN;            // 16384*128
  unsigned short* kws = qws + (size_t)NROWS * DD;
  unsigned short* vws = kws + (size_t)NROWS * DD;          // [4][128][4096]

  build_wt<<<dim3(384), dim3(256), 0, stream>>>(Wq, Wk, Wv, Wh, Wl);
  proj_qkv<<<dim3(128, 3), dim3(256), 0, stream>>>(x, Wh, Wl, qws, kws, vws);
  attn_fused<<<dim3(64, 4), dim3(256), 0, stream>>>(qws, kws, vws, out, att);
}